// Round 10
// baseline (159.440 us; speedup 1.0000x reference)
//
#include <hip/hip_runtime.h>
#include <hip/hip_bf16.h>

// GAT forward on MI355X. N=4096, IN_F=512, OUT_F=64, HEADS=4, alpha=0.2.
//
// R9 post-mortem: 80KB-LDS attn => 1 block/CU (occupancy regression); revert
// to R8. R10 = R8 + attn occupancy fix: 2-round LDS tree combine (72->40KB
// => 3 blocks/CU), launch_bounds(512,6) (VGPR<=85 => 24 waves/CU), and V
// fragments nt-interleaved so V loads are 2x dwordx4 instead of 4x dwordx2.
// K1: xpack+wpack   K2: gemmfuse+adjpack   K3: attn

#define NN 4096
#define KF 512
#define NF 256

typedef __attribute__((ext_vector_type(8))) short bf16x8;
typedef __attribute__((ext_vector_type(4))) short s16x4;
typedef __attribute__((ext_vector_type(4))) float f32x4;

union AB8 { bf16x8 v; short2 h[4]; short s[8]; int4 i4; };
union ST4 { s16x4 v; short2 h[2]; };
union I64 { long v; int i[2]; };
union V16 { int4 q; long l[2]; };

__device__ __forceinline__ short f2bf(float f) {
    union { float f; unsigned u; } v; v.f = f;
    unsigned r = v.u + 0x7fffu + ((v.u >> 16) & 1u);  // RNE (finite only)
    return (short)(r >> 16);
}
__device__ __forceinline__ short2 pkbf(float a, float b) {
    __hip_bfloat162 t = __float22bfloat162_rn(make_float2(a, b));
    union { __hip_bfloat162 v; short2 s; } u; u.v = t;
    return u.s;
}
__device__ __forceinline__ int pkfp8x4(float a, float b, float c, float d) {
    int p = __builtin_amdgcn_cvt_pk_fp8_f32(a, b, 0, false);
    p     = __builtin_amdgcn_cvt_pk_fp8_f32(c, d, p, true);
    return p;
}

// ---------------- K1: xpack (bid<1024) + wpack (bid>=1024) ----------------
__global__ __launch_bounds__(256) void stage1(const float* __restrict__ x,
                                              const float* __restrict__ W,
                                              short* __restrict__ xF,
                                              short* __restrict__ WtF) {
    if (blockIdx.x < 1024) {
        const int lane = threadIdx.x & 63, wv = threadIdx.x >> 6;
        const int i = blockIdx.x * 4 + wv;
        const float4* xp = (const float4*)(x + (size_t)i * KF + lane * 8);
        float4 xa = xp[0], xb = xp[1];
        ST4 o0, o1;
        o0.h[0] = pkbf(xa.x, xa.y); o0.h[1] = pkbf(xa.z, xa.w);
        o1.h[0] = pkbf(xb.x, xb.y); o1.h[1] = pkbf(xb.z, xb.w);
        const int kblk = lane >> 2, qk = lane & 3;
        const int jgrp = i >> 4, r = i & 15;
        short* dst = xF + ((size_t)(kblk * 256 + jgrp) * 64 + qk * 16 + r) * 8;
        *(s16x4*)dst = o0.v;
        *(s16x4*)(dst + 4) = o1.v;
    } else {
        int tid = (blockIdx.x - 1024) * 256 + threadIdx.x;   // 16384 threads
        int l = tid & 63, nt = (tid >> 6) & 3, hd = (tid >> 8) & 3, kblk = tid >> 10;
        int q = l >> 4, r = l & 15;
        int col = hd * 64 + nt * 16 + r;
        int k0 = kblk * 32 + q * 8;
        AB8 o;
        #pragma unroll
        for (int e = 0; e < 8; e++) o.s[e] = f2bf(W[(k0 + e) * NF + col]);
        *(bf16x8*)(WtF + (size_t)tid * 8) = o.v;
    }
}

// ---------------- K2: gemmfuse (bid<256) + adjpack (bid>=256) ----------------
__global__ __launch_bounds__(256) void stage2(const short* __restrict__ xF,
                                              const short* __restrict__ WtF,
                                              const float* __restrict__ a,
                                              const int* __restrict__ adj,
                                              unsigned char* __restrict__ VtF8,
                                              float* __restrict__ ipk,
                                              float2* __restrict__ jpk,
                                              unsigned* __restrict__ pT) {
    if (blockIdx.x < 256) {
        const int lane = threadIdx.x & 63, wv = threadIdx.x >> 6;
        const int q = lane >> 4, r = lane & 15;
        const int jb32 = blockIdx.x >> 1, ch = blockIdx.x & 1;
        const int rg = wv >> 1, hd = ch * 2 + (wv & 1);
        const int jgrp = jb32 * 2 + rg;

        const short* ap = xF  + ((size_t)jgrp * 64 + lane) * 8;
        const short* wp = WtF + ((size_t)(hd * 4) * 64 + lane) * 8;

        f32x4 acc[4] = {};
        #pragma unroll
        for (int kblk = 0; kblk < 16; kblk++) {
            bf16x8 av = *(const bf16x8*)(ap + (size_t)kblk * 256 * 512);
            const short* w = wp + (size_t)kblk * 16 * 512;
            #pragma unroll
            for (int nt = 0; nt < 4; nt++) {
                bf16x8 bv = *(const bf16x8*)(w + nt * 512);
                acc[nt] = __builtin_amdgcn_mfma_f32_16x16x32_bf16(av, bv, acc[nt], 0, 0, 0);
            }
        }
        // V store, nt-interleaved: byte addr = (((jb32*4+hd)*64 + qa*16+r)*4 + nt)*8 + e0
        const int base = rg * 16 + q * 4;
        const int qa = base >> 3, e0 = base & 7;
        #pragma unroll
        for (int nt = 0; nt < 4; nt++) {
            size_t addr = ((size_t)((jb32 * 4 + hd) * 64 + qa * 16 + r) * 4 + nt) * 8 + e0;
            *(int*)(VtF8 + addr) = pkfp8x4(acc[nt][0], acc[nt][1], acc[nt][2], acc[nt][3]);
        }
        float as[4], at[4];
        #pragma unroll
        for (int nt = 0; nt < 4; nt++) { as[nt] = a[nt * 16 + r]; at[nt] = a[64 + nt * 16 + r]; }
        f32x4 sp = {}, tp = {};
        #pragma unroll
        for (int nt = 0; nt < 4; nt++)
            #pragma unroll
            for (int reg = 0; reg < 4; reg++) {
                sp[reg] += acc[nt][reg] * as[nt];
                tp[reg] += acc[nt][reg] * at[nt];
            }
        #pragma unroll
        for (int d = 1; d < 16; d <<= 1)
            #pragma unroll
            for (int reg = 0; reg < 4; reg++) {
                sp[reg] += __shfl_xor(sp[reg], d, 64);
                tp[reg] += __shfl_xor(tp[reg], d, 64);
            }
        if (r == 0) {
            #pragma unroll
            for (int reg = 0; reg < 4; reg++) {
                int j = jb32 * 32 + rg * 16 + q * 4 + reg;
                ipk[hd * NN + j] = __expf(-0.8f * sp[reg]);
                jpk[hd * NN + j] = make_float2(__expf(tp[reg]), __expf(0.2f * tp[reg]));
            }
        }
    } else {
        int gw   = ((blockIdx.x - 256) * 256 + threadIdx.x) >> 6;
        int lane = threadIdx.x & 63;
        int i = gw >> 4, seg = gw & 15;
        const int* ap = adj + (size_t)i * NN + seg * 256 + lane;
        unsigned long long b0 = __ballot(ap[0]   != 0);
        unsigned long long b1 = __ballot(ap[64]  != 0);
        unsigned long long b2 = __ballot(ap[128] != 0);
        unsigned long long b3 = __ballot(ap[192] != 0);
        if (lane == 0) {
            *(uint4*)(pT + ((size_t)(seg * 2    ) * NN + i) * 4) =
                make_uint4((unsigned)b0, (unsigned)(b0 >> 32), (unsigned)b1, (unsigned)(b1 >> 32));
            *(uint4*)(pT + ((size_t)(seg * 2 + 1) * NN + i) * 4) =
                make_uint4((unsigned)b2, (unsigned)(b2 >> 32), (unsigned)b3, (unsigned)(b3 >> 32));
        }
    }
}

// ---------------- K3: attn v5 -- 2 i-tiles/wave, LUT mask, fp8 P@V ----------------
// grid 512 = 128 itile32 x 4 heads; block 512 = 8 waves = 8 j-eighths (16 iters).
// launch_bounds(512,6): VGPR<=85; LDS 40KB => 3 blocks/CU = 24 waves/CU.
__global__ __launch_bounds__(512, 6)
void gat_attn(const uint4* __restrict__ pT4, const float* __restrict__ ipk,
              const float* __restrict__ jpkf, const unsigned char* __restrict__ VtF8,
              float* __restrict__ out) {
    const int lane = threadIdx.x & 63, js = threadIdx.x >> 6;   // j-eighth 0..7
    const int hd = blockIdx.x & 3, it32 = blockIdx.x >> 2;
    const int q = lane >> 4, r = lane & 15;
    const int i0 = it32 * 32, ia = i0 + r;
    const float cia = ipk[hd * NN + ia];
    const float cib = ipk[hd * NN + ia + 16];
    const int qs = q * 8;

    __shared__ unsigned lut[16];
    __shared__ float sacc[4][10][64][4];   // 40960 B (2-round tree combine)
    if (threadIdx.x < 16) {
        unsigned m01 = (threadIdx.x * 0x204081u) & 0x01010101u;
        lut[threadIdx.x] = m01 * 0xFFu;    // byte e = 0xFF iff bit e of idx
    }
    __syncthreads();

    f32x4 acc[10] = {};
    const long ones = 0x3838383838383838L;      // fp8 e4m3 1.0 bytes

    const int it0 = js * 16;
    const float* jp = jpkf + (size_t)hd * NN * 2 + 2 * ((it0 << 5) + qs);
    const int4*  vq = (const int4*)(VtF8 + ((size_t)(it0 * 4 + hd) * 64 + lane) * 32);
    const uint4* prow = pT4 + (size_t)(js * 4) * NN + ia;

    auto iset = [&](unsigned w, float ci, f32x4* ac,
                    float4 ja, float4 jb, float4 jc, float4 jd,
                    long v0, long v1, long v2, long v3) {
        float p0 = fmaxf(ja.x, ci * ja.y);
        float p1 = fmaxf(ja.z, ci * ja.w);
        float p2 = fmaxf(jb.x, ci * jb.y);
        float p3 = fmaxf(jb.z, ci * jb.w);
        float p4 = fmaxf(jc.x, ci * jc.y);
        float p5 = fmaxf(jc.z, ci * jc.w);
        float p6 = fmaxf(jd.x, ci * jd.y);
        float p7 = fmaxf(jd.z, ci * jd.w);
        I64 af;
        af.i[0] = pkfp8x4(p0, p1, p2, p3) & (int)lut[w & 15u];
        af.i[1] = pkfp8x4(p4, p5, p6, p7) & (int)lut[(w >> 4) & 15u];
        ac[0] = __builtin_amdgcn_mfma_f32_16x16x32_fp8_fp8(af.v, v0, ac[0], 0, 0, 0);
        ac[1] = __builtin_amdgcn_mfma_f32_16x16x32_fp8_fp8(af.v, v1, ac[1], 0, 0, 0);
        ac[2] = __builtin_amdgcn_mfma_f32_16x16x32_fp8_fp8(af.v, v2, ac[2], 0, 0, 0);
        ac[3] = __builtin_amdgcn_mfma_f32_16x16x32_fp8_fp8(af.v, v3, ac[3], 0, 0, 0);
        ac[4] = __builtin_amdgcn_mfma_f32_16x16x32_fp8_fp8(af.v, ones, ac[4], 0, 0, 0);
    };

    #pragma unroll 1
    for (int g = 0; g < 4; g++) {
        uint4 wga = prow[(size_t)g * NN];
        uint4 wgb = prow[(size_t)g * NN + 16];
        #pragma unroll
        for (int u = 0; u < 4; u++) {
            unsigned wa = (u == 0 ? wga.x : u == 1 ? wga.y : u == 2 ? wga.z : wga.w) >> qs;
            unsigned wb = (u == 0 ? wgb.x : u == 1 ? wgb.y : u == 2 ? wgb.z : wgb.w) >> qs;
            const float4* jpv = (const float4*)jp;
            float4 ja = jpv[0], jb = jpv[1], jc = jpv[2], jd = jpv[3];
            V16 va, vb; va.q = vq[0]; vb.q = vq[1];
            iset(wa, cia, acc,     ja, jb, jc, jd, va.l[0], va.l[1], vb.l[0], vb.l[1]);
            iset(wb, cib, acc + 5, ja, jb, jc, jd, va.l[0], va.l[1], vb.l[0], vb.l[1]);
            jp += 64; vq += 512;
        }
    }

    // 2-round tree combine: 8 waves -> 1 (LDS reused, 40KB).
    if (js >= 4) {
        #pragma unroll
        for (int t = 0; t < 10; t++)
            *(f32x4*)&sacc[js - 4][t][lane][0] = acc[t];
    }
    __syncthreads();
    if (js < 4) {
        #pragma unroll
        for (int t = 0; t < 10; t++) {
            f32x4 o = *(const f32x4*)&sacc[js][t][lane][0];
            acc[t][0] += o[0]; acc[t][1] += o[1];
            acc[t][2] += o[2]; acc[t][3] += o[3];
        }
    }
    __syncthreads();
    if (js >= 1 && js < 4) {
        #pragma unroll
        for (int t = 0; t < 10; t++)
            *(f32x4*)&sacc[js - 1][t][lane][0] = acc[t];
    }
    __syncthreads();
    if (js == 0) {
        #pragma unroll 1
        for (int gg = 0; gg < 3; gg++)
            #pragma unroll
            for (int t = 0; t < 10; t++) {
                f32x4 o = *(const f32x4*)&sacc[gg][t][lane][0];
                acc[t][0] += o[0]; acc[t][1] += o[1];
                acc[t][2] += o[2]; acc[t][3] += o[3];
            }
        #pragma unroll
        for (int reg = 0; reg < 4; reg++) {
            float inva = 1.f / acc[4][reg];
            float invb = 1.f / acc[9][reg];
            int rowa = i0 + q * 4 + reg;
            #pragma unroll
            for (int t = 0; t < 4; t++) {
                out[(size_t)rowa * NF + hd * 64 + t * 16 + r] = acc[t][reg] * inva;
                out[(size_t)(rowa + 16) * NF + hd * 64 + t * 16 + r] = acc[t + 5][reg] * invb;
            }
        }
    }
}

extern "C" void kernel_launch(void* const* d_in, const int* in_sizes, int n_in,
                              void* d_out, int out_size, void* d_ws, size_t ws_size,
                              hipStream_t stream) {
    const float* x   = (const float*)d_in[0];
    const int*   adj = (const int*)d_in[1];
    const float* W   = (const float*)d_in[2];
    const float* a   = (const float*)d_in[3];
    float* out = (float*)d_out;

    char* ws = (char*)d_ws;
    short*         xF   = (short*)ws;                      // 4 MiB
    short*         WtF  = (short*)(ws + 4194304);          // 256 KiB
    unsigned char* VtF8 = (unsigned char*)(ws + 4456448);  // 1 MiB
    unsigned*      pT   = (unsigned*)(ws + 5505024);       // 2 MiB
    float*         ipk  = (float*)(ws + 7602176);          // 64 KiB
    float2*        jpk  = (float2*)(ws + 7667712);         // 128 KiB

    stage1  <<<1088, 256, 0, stream>>>(x, W, xF, WtF);
    stage2  <<<16640, 256, 0, stream>>>(xF, WtF, a, adj, VtF8, ipk, jpk, pT);
    gat_attn<<<512, 512, 0, stream>>>((const uint4*)pT, ipk, (const float*)jpk, VtF8, out);
}

// Round 11
// 143.595 us; speedup vs baseline: 1.1103x; 1.1103x over previous
//
#include <hip/hip_runtime.h>
#include <hip/hip_bf16.h>

// GAT forward on MI355X. N=4096, IN_F=512, OUT_F=64, HEADS=4, alpha=0.2.
//
// R10 post-mortem: waves_per_eu=6 register-starved attn (VGPR_Count=40,
// 88 MB spill traffic, 53us). R11 = revert to R8 structure (VGPR<=128,
// 72KB 1-sync combine) + latency-chain cuts: arithmetic byte-mask (no LDS
// LUT dependency), upfront pT prefetch (no HBM load in loop), dwordx4 V.
// K1: xpack+wpack   K2: gemmfuse+adjpack   K3: attn

#define NN 4096
#define KF 512
#define NF 256

typedef __attribute__((ext_vector_type(8))) short bf16x8;
typedef __attribute__((ext_vector_type(4))) short s16x4;
typedef __attribute__((ext_vector_type(4))) float f32x4;

union AB8 { bf16x8 v; short2 h[4]; short s[8]; int4 i4; };
union ST4 { s16x4 v; short2 h[2]; };
union I64 { long v; int i[2]; };
union V16 { int4 q; long l[2]; };

__device__ __forceinline__ short f2bf(float f) {
    union { float f; unsigned u; } v; v.f = f;
    unsigned r = v.u + 0x7fffu + ((v.u >> 16) & 1u);  // RNE (finite only)
    return (short)(r >> 16);
}
__device__ __forceinline__ short2 pkbf(float a, float b) {
    __hip_bfloat162 t = __float22bfloat162_rn(make_float2(a, b));
    union { __hip_bfloat162 v; short2 s; } u; u.v = t;
    return u.s;
}
__device__ __forceinline__ int pkfp8x4(float a, float b, float c, float d) {
    int p = __builtin_amdgcn_cvt_pk_fp8_f32(a, b, 0, false);
    p     = __builtin_amdgcn_cvt_pk_fp8_f32(c, d, p, true);
    return p;
}
// nibble n -> 4 bytes, byte e = 0xFF iff bit e of n (3 VALU ops, no LDS)
__device__ __forceinline__ int bytemask(unsigned n) {
    return (int)(((n * 0x204081u) & 0x01010101u) * 0xFFu);
}

// ---------------- K1: xpack (bid<1024) + wpack (bid>=1024) ----------------
__global__ __launch_bounds__(256) void stage1(const float* __restrict__ x,
                                              const float* __restrict__ W,
                                              short* __restrict__ xF,
                                              short* __restrict__ WtF) {
    if (blockIdx.x < 1024) {
        const int lane = threadIdx.x & 63, wv = threadIdx.x >> 6;
        const int i = blockIdx.x * 4 + wv;
        const float4* xp = (const float4*)(x + (size_t)i * KF + lane * 8);
        float4 xa = xp[0], xb = xp[1];
        ST4 o0, o1;
        o0.h[0] = pkbf(xa.x, xa.y); o0.h[1] = pkbf(xa.z, xa.w);
        o1.h[0] = pkbf(xb.x, xb.y); o1.h[1] = pkbf(xb.z, xb.w);
        const int kblk = lane >> 2, qk = lane & 3;
        const int jgrp = i >> 4, r = i & 15;
        short* dst = xF + ((size_t)(kblk * 256 + jgrp) * 64 + qk * 16 + r) * 8;
        *(s16x4*)dst = o0.v;
        *(s16x4*)(dst + 4) = o1.v;
    } else {
        int tid = (blockIdx.x - 1024) * 256 + threadIdx.x;   // 16384 threads
        int l = tid & 63, nt = (tid >> 6) & 3, hd = (tid >> 8) & 3, kblk = tid >> 10;
        int q = l >> 4, r = l & 15;
        int col = hd * 64 + nt * 16 + r;
        int k0 = kblk * 32 + q * 8;
        AB8 o;
        #pragma unroll
        for (int e = 0; e < 8; e++) o.s[e] = f2bf(W[(k0 + e) * NF + col]);
        *(bf16x8*)(WtF + (size_t)tid * 8) = o.v;
    }
}

// ---------------- K2: gemmfuse (bid<256) + adjpack (bid>=256) ----------------
__global__ __launch_bounds__(256) void stage2(const short* __restrict__ xF,
                                              const short* __restrict__ WtF,
                                              const float* __restrict__ a,
                                              const int* __restrict__ adj,
                                              unsigned char* __restrict__ VtF8,
                                              float* __restrict__ ipk,
                                              float2* __restrict__ jpk,
                                              unsigned* __restrict__ pT) {
    if (blockIdx.x < 256) {
        const int lane = threadIdx.x & 63, wv = threadIdx.x >> 6;
        const int q = lane >> 4, r = lane & 15;
        const int jb32 = blockIdx.x >> 1, ch = blockIdx.x & 1;
        const int rg = wv >> 1, hd = ch * 2 + (wv & 1);
        const int jgrp = jb32 * 2 + rg;

        const short* ap = xF  + ((size_t)jgrp * 64 + lane) * 8;
        const short* wp = WtF + ((size_t)(hd * 4) * 64 + lane) * 8;

        f32x4 acc[4] = {};
        #pragma unroll
        for (int kblk = 0; kblk < 16; kblk++) {
            bf16x8 av = *(const bf16x8*)(ap + (size_t)kblk * 256 * 512);
            const short* w = wp + (size_t)kblk * 16 * 512;
            #pragma unroll
            for (int nt = 0; nt < 4; nt++) {
                bf16x8 bv = *(const bf16x8*)(w + nt * 512);
                acc[nt] = __builtin_amdgcn_mfma_f32_16x16x32_bf16(av, bv, acc[nt], 0, 0, 0);
            }
        }
        // V store, nt-interleaved: byte addr = (((jb32*4+hd)*64 + qa*16+r)*4 + nt)*8 + e0
        const int base = rg * 16 + q * 4;
        const int qa = base >> 3, e0 = base & 7;
        #pragma unroll
        for (int nt = 0; nt < 4; nt++) {
            size_t addr = ((size_t)((jb32 * 4 + hd) * 64 + qa * 16 + r) * 4 + nt) * 8 + e0;
            *(int*)(VtF8 + addr) = pkfp8x4(acc[nt][0], acc[nt][1], acc[nt][2], acc[nt][3]);
        }
        float as[4], at[4];
        #pragma unroll
        for (int nt = 0; nt < 4; nt++) { as[nt] = a[nt * 16 + r]; at[nt] = a[64 + nt * 16 + r]; }
        f32x4 sp = {}, tp = {};
        #pragma unroll
        for (int nt = 0; nt < 4; nt++)
            #pragma unroll
            for (int reg = 0; reg < 4; reg++) {
                sp[reg] += acc[nt][reg] * as[nt];
                tp[reg] += acc[nt][reg] * at[nt];
            }
        #pragma unroll
        for (int d = 1; d < 16; d <<= 1)
            #pragma unroll
            for (int reg = 0; reg < 4; reg++) {
                sp[reg] += __shfl_xor(sp[reg], d, 64);
                tp[reg] += __shfl_xor(tp[reg], d, 64);
            }
        if (r == 0) {
            #pragma unroll
            for (int reg = 0; reg < 4; reg++) {
                int j = jb32 * 32 + rg * 16 + q * 4 + reg;
                ipk[hd * NN + j] = __expf(-0.8f * sp[reg]);
                jpk[hd * NN + j] = make_float2(__expf(tp[reg]), __expf(0.2f * tp[reg]));
            }
        }
    } else {
        int gw   = ((blockIdx.x - 256) * 256 + threadIdx.x) >> 6;
        int lane = threadIdx.x & 63;
        int i = gw >> 4, seg = gw & 15;
        const int* ap = adj + (size_t)i * NN + seg * 256 + lane;
        unsigned long long b0 = __ballot(ap[0]   != 0);
        unsigned long long b1 = __ballot(ap[64]  != 0);
        unsigned long long b2 = __ballot(ap[128] != 0);
        unsigned long long b3 = __ballot(ap[192] != 0);
        if (lane == 0) {
            *(uint4*)(pT + ((size_t)(seg * 2    ) * NN + i) * 4) =
                make_uint4((unsigned)b0, (unsigned)(b0 >> 32), (unsigned)b1, (unsigned)(b1 >> 32));
            *(uint4*)(pT + ((size_t)(seg * 2 + 1) * NN + i) * 4) =
                make_uint4((unsigned)b2, (unsigned)(b2 >> 32), (unsigned)b3, (unsigned)(b3 >> 32));
        }
    }
}

// ---------------- K3: attn v6 -- R8 structure + latency-chain cuts ----------------
// grid 512 = 128 itile32 x 4 heads; block 512 = 8 waves = 8 j-eighths (16 iters).
// launch_bounds(512,4): VGPR<=128, LDS 72KB => 2 blocks/CU = 16 waves/CU.
__global__ __launch_bounds__(512, 4)
void gat_attn(const uint4* __restrict__ pT4, const float* __restrict__ ipk,
              const float* __restrict__ jpkf, const unsigned char* __restrict__ VtF8,
              float* __restrict__ out) {
    const int lane = threadIdx.x & 63, js = threadIdx.x >> 6;   // j-eighth 0..7
    const int hd = blockIdx.x & 3, it32 = blockIdx.x >> 2;
    const int q = lane >> 4, r = lane & 15;
    const int i0 = it32 * 32, ia = i0 + r;
    const float cia = ipk[hd * NN + ia];
    const float cib = ipk[hd * NN + ia + 16];
    const int qs = q * 8;

    __shared__ float sacc[7][10][64][4];   // 71680 B (1-sync combine, R8 style)

    f32x4 acc[10] = {};
    const long ones = 0x3838383838383838L;      // fp8 e4m3 1.0 bytes

    const int it0 = js * 16;
    const float* jp = jpkf + (size_t)hd * NN * 2 + 2 * ((it0 << 5) + qs);
    const int4*  vq = (const int4*)(VtF8 + ((size_t)(it0 * 4 + hd) * 64 + lane) * 32);
    const uint4* prow = pT4 + (size_t)(js * 4) * NN + ia;

    // upfront adj prefetch: all 8 words (4 groups x 2 i-tiles) into registers
    uint4 WA[4], WB[4];
    #pragma unroll
    for (int g = 0; g < 4; g++) {
        WA[g] = prow[(size_t)g * NN];
        WB[g] = prow[(size_t)g * NN + 16];
    }

    auto iset = [&](unsigned w, float ci, f32x4* ac,
                    float4 ja, float4 jb, float4 jc, float4 jd,
                    long v0, long v1, long v2, long v3) {
        float p0 = fmaxf(ja.x, ci * ja.y);
        float p1 = fmaxf(ja.z, ci * ja.w);
        float p2 = fmaxf(jb.x, ci * jb.y);
        float p3 = fmaxf(jb.z, ci * jb.w);
        float p4 = fmaxf(jc.x, ci * jc.y);
        float p5 = fmaxf(jc.z, ci * jc.w);
        float p6 = fmaxf(jd.x, ci * jd.y);
        float p7 = fmaxf(jd.z, ci * jd.w);
        I64 af;
        af.i[0] = pkfp8x4(p0, p1, p2, p3) & bytemask(w & 15u);
        af.i[1] = pkfp8x4(p4, p5, p6, p7) & bytemask((w >> 4) & 15u);
        ac[0] = __builtin_amdgcn_mfma_f32_16x16x32_fp8_fp8(af.v, v0, ac[0], 0, 0, 0);
        ac[1] = __builtin_amdgcn_mfma_f32_16x16x32_fp8_fp8(af.v, v1, ac[1], 0, 0, 0);
        ac[2] = __builtin_amdgcn_mfma_f32_16x16x32_fp8_fp8(af.v, v2, ac[2], 0, 0, 0);
        ac[3] = __builtin_amdgcn_mfma_f32_16x16x32_fp8_fp8(af.v, v3, ac[3], 0, 0, 0);
        ac[4] = __builtin_amdgcn_mfma_f32_16x16x32_fp8_fp8(af.v, ones, ac[4], 0, 0, 0);
    };

    #pragma unroll 1
    for (int g = 0; g < 4; g++) {
        uint4 wga = WA[g], wgb = WB[g];
        #pragma unroll
        for (int u = 0; u < 4; u++) {
            unsigned wa = (u == 0 ? wga.x : u == 1 ? wga.y : u == 2 ? wga.z : wga.w) >> qs;
            unsigned wb = (u == 0 ? wgb.x : u == 1 ? wgb.y : u == 2 ? wgb.z : wgb.w) >> qs;
            const float4* jpv = (const float4*)jp;
            float4 ja = jpv[0], jb = jpv[1], jc = jpv[2], jd = jpv[3];
            V16 va, vb; va.q = vq[0]; vb.q = vq[1];
            iset(wa, cia, acc,     ja, jb, jc, jd, va.l[0], va.l[1], vb.l[0], vb.l[1]);
            iset(wb, cib, acc + 5, ja, jb, jc, jd, va.l[0], va.l[1], vb.l[0], vb.l[1]);
            jp += 64; vq += 512;
        }
    }

    // 1-sync combine (R8): waves 1-7 dump, wave 0 accumulates.
    if (js > 0) {
        #pragma unroll
        for (int t = 0; t < 10; t++)
            *(f32x4*)&sacc[js - 1][t][lane][0] = acc[t];
    }
    __syncthreads();
    if (js == 0) {
        #pragma unroll 1
        for (int gg = 0; gg < 7; gg++)
            #pragma unroll
            for (int t = 0; t < 10; t++) {
                f32x4 o = *(const f32x4*)&sacc[gg][t][lane][0];
                acc[t][0] += o[0]; acc[t][1] += o[1];
                acc[t][2] += o[2]; acc[t][3] += o[3];
            }
        #pragma unroll
        for (int reg = 0; reg < 4; reg++) {
            float inva = 1.f / acc[4][reg];
            float invb = 1.f / acc[9][reg];
            int rowa = i0 + q * 4 + reg;
            #pragma unroll
            for (int t = 0; t < 4; t++) {
                out[(size_t)rowa * NF + hd * 64 + t * 16 + r] = acc[t][reg] * inva;
                out[(size_t)(rowa + 16) * NF + hd * 64 + t * 16 + r] = acc[t + 5][reg] * invb;
            }
        }
    }
}

extern "C" void kernel_launch(void* const* d_in, const int* in_sizes, int n_in,
                              void* d_out, int out_size, void* d_ws, size_t ws_size,
                              hipStream_t stream) {
    const float* x   = (const float*)d_in[0];
    const int*   adj = (const int*)d_in[1];
    const float* W   = (const float*)d_in[2];
    const float* a   = (const float*)d_in[3];
    float* out = (float*)d_out;

    char* ws = (char*)d_ws;
    short*         xF   = (short*)ws;                      // 4 MiB
    short*         WtF  = (short*)(ws + 4194304);          // 256 KiB
    unsigned char* VtF8 = (unsigned char*)(ws + 4456448);  // 1 MiB
    unsigned*      pT   = (unsigned*)(ws + 5505024);       // 2 MiB
    float*         ipk  = (float*)(ws + 7602176);          // 64 KiB
    float2*        jpk  = (float2*)(ws + 7667712);         // 128 KiB

    stage1  <<<1088, 256, 0, stream>>>(x, W, xF, WtF);
    stage2  <<<16640, 256, 0, stream>>>(xF, WtF, a, adj, VtF8, ipk, jpk, pT);
    gat_attn<<<512, 512, 0, stream>>>((const uint4*)pT, ipk, (const float*)jpk, VtF8, out);
}

// Round 12
// 128.174 us; speedup vs baseline: 1.2439x; 1.1203x over previous
//
#include <hip/hip_runtime.h>
#include <hip/hip_bf16.h>

// GAT forward on MI355X. N=4096, IN_F=512, OUT_F=64, HEADS=4, alpha=0.2.
//
// R9-R11 post-mortem: R8 is a sharp local optimum (VGPR<=128, 72KB LDS,
// LUT mask). R9 (LDS up) -> 1 blk/CU; R10 (VGPR cap 85) -> spill; R11
// (32-VGPR held prefetch) -> spill. R12 = exact R8 + ONE cheap change:
// pT group loads prefetched one g ahead (8 VGPRs, consumed within 4 iters)
// to hide the every-4th-iter cross-XCD pT stall.
// K1: xpack+wpack   K2: gemmfuse+adjpack   K3: attn

#define NN 4096
#define KF 512
#define NF 256

typedef __attribute__((ext_vector_type(8))) short bf16x8;
typedef __attribute__((ext_vector_type(4))) short s16x4;
typedef __attribute__((ext_vector_type(4))) float f32x4;

union AB8 { bf16x8 v; short2 h[4]; short s[8]; int4 i4; };
union ST4 { s16x4 v; short2 h[2]; };
union I64 { long v; int i[2]; };

__device__ __forceinline__ short f2bf(float f) {
    union { float f; unsigned u; } v; v.f = f;
    unsigned r = v.u + 0x7fffu + ((v.u >> 16) & 1u);  // RNE (finite only)
    return (short)(r >> 16);
}
__device__ __forceinline__ short2 pkbf(float a, float b) {
    __hip_bfloat162 t = __float22bfloat162_rn(make_float2(a, b));
    union { __hip_bfloat162 v; short2 s; } u; u.v = t;
    return u.s;
}
__device__ __forceinline__ int pkfp8x4(float a, float b, float c, float d) {
    int p = __builtin_amdgcn_cvt_pk_fp8_f32(a, b, 0, false);
    p     = __builtin_amdgcn_cvt_pk_fp8_f32(c, d, p, true);
    return p;
}

// ---------------- K1: xpack (bid<1024) + wpack (bid>=1024) ----------------
__global__ __launch_bounds__(256) void stage1(const float* __restrict__ x,
                                              const float* __restrict__ W,
                                              short* __restrict__ xF,
                                              short* __restrict__ WtF) {
    if (blockIdx.x < 1024) {
        const int lane = threadIdx.x & 63, wv = threadIdx.x >> 6;
        const int i = blockIdx.x * 4 + wv;
        const float4* xp = (const float4*)(x + (size_t)i * KF + lane * 8);
        float4 xa = xp[0], xb = xp[1];
        ST4 o0, o1;
        o0.h[0] = pkbf(xa.x, xa.y); o0.h[1] = pkbf(xa.z, xa.w);
        o1.h[0] = pkbf(xb.x, xb.y); o1.h[1] = pkbf(xb.z, xb.w);
        const int kblk = lane >> 2, qk = lane & 3;
        const int jgrp = i >> 4, r = i & 15;
        short* dst = xF + ((size_t)(kblk * 256 + jgrp) * 64 + qk * 16 + r) * 8;
        *(s16x4*)dst = o0.v;
        *(s16x4*)(dst + 4) = o1.v;
    } else {
        int tid = (blockIdx.x - 1024) * 256 + threadIdx.x;   // 16384 threads
        int l = tid & 63, nt = (tid >> 6) & 3, hd = (tid >> 8) & 3, kblk = tid >> 10;
        int q = l >> 4, r = l & 15;
        int col = hd * 64 + nt * 16 + r;
        int k0 = kblk * 32 + q * 8;
        AB8 o;
        #pragma unroll
        for (int e = 0; e < 8; e++) o.s[e] = f2bf(W[(k0 + e) * NF + col]);
        *(bf16x8*)(WtF + (size_t)tid * 8) = o.v;
    }
}

// ---------------- K2: gemmfuse (bid<256) + adjpack (bid>=256) ----------------
__global__ __launch_bounds__(256) void stage2(const short* __restrict__ xF,
                                              const short* __restrict__ WtF,
                                              const float* __restrict__ a,
                                              const int* __restrict__ adj,
                                              unsigned char* __restrict__ VtF8,
                                              float* __restrict__ ipk,
                                              float2* __restrict__ jpk,
                                              unsigned* __restrict__ pT) {
    if (blockIdx.x < 256) {
        const int lane = threadIdx.x & 63, wv = threadIdx.x >> 6;
        const int q = lane >> 4, r = lane & 15;
        const int jb32 = blockIdx.x >> 1, ch = blockIdx.x & 1;
        const int rg = wv >> 1, hd = ch * 2 + (wv & 1);
        const int jgrp = jb32 * 2 + rg;

        const short* ap = xF  + ((size_t)jgrp * 64 + lane) * 8;
        const short* wp = WtF + ((size_t)(hd * 4) * 64 + lane) * 8;

        f32x4 acc[4] = {};
        #pragma unroll
        for (int kblk = 0; kblk < 16; kblk++) {
            bf16x8 av = *(const bf16x8*)(ap + (size_t)kblk * 256 * 512);
            const short* w = wp + (size_t)kblk * 16 * 512;
            #pragma unroll
            for (int nt = 0; nt < 4; nt++) {
                bf16x8 bv = *(const bf16x8*)(w + nt * 512);
                acc[nt] = __builtin_amdgcn_mfma_f32_16x16x32_bf16(av, bv, acc[nt], 0, 0, 0);
            }
        }
        const int base = rg * 16 + q * 4;
        const int qa = base >> 3, e0 = base & 7;
        #pragma unroll
        for (int nt = 0; nt < 4; nt++) {
            size_t slot = (size_t)(((jb32 * 4 + hd) * 4 + nt) * 64 + qa * 16 + r);
            *(int*)(VtF8 + slot * 8 + e0) = pkfp8x4(acc[nt][0], acc[nt][1], acc[nt][2], acc[nt][3]);
        }
        float as[4], at[4];
        #pragma unroll
        for (int nt = 0; nt < 4; nt++) { as[nt] = a[nt * 16 + r]; at[nt] = a[64 + nt * 16 + r]; }
        f32x4 sp = {}, tp = {};
        #pragma unroll
        for (int nt = 0; nt < 4; nt++)
            #pragma unroll
            for (int reg = 0; reg < 4; reg++) {
                sp[reg] += acc[nt][reg] * as[nt];
                tp[reg] += acc[nt][reg] * at[nt];
            }
        #pragma unroll
        for (int d = 1; d < 16; d <<= 1)
            #pragma unroll
            for (int reg = 0; reg < 4; reg++) {
                sp[reg] += __shfl_xor(sp[reg], d, 64);
                tp[reg] += __shfl_xor(tp[reg], d, 64);
            }
        if (r == 0) {
            #pragma unroll
            for (int reg = 0; reg < 4; reg++) {
                int j = jb32 * 32 + rg * 16 + q * 4 + reg;
                ipk[hd * NN + j] = __expf(-0.8f * sp[reg]);
                jpk[hd * NN + j] = make_float2(__expf(tp[reg]), __expf(0.2f * tp[reg]));
            }
        }
    } else {
        int gw   = ((blockIdx.x - 256) * 256 + threadIdx.x) >> 6;
        int lane = threadIdx.x & 63;
        int i = gw >> 4, seg = gw & 15;
        const int* ap = adj + (size_t)i * NN + seg * 256 + lane;
        unsigned long long b0 = __ballot(ap[0]   != 0);
        unsigned long long b1 = __ballot(ap[64]  != 0);
        unsigned long long b2 = __ballot(ap[128] != 0);
        unsigned long long b3 = __ballot(ap[192] != 0);
        if (lane == 0) {
            *(uint4*)(pT + ((size_t)(seg * 2    ) * NN + i) * 4) =
                make_uint4((unsigned)b0, (unsigned)(b0 >> 32), (unsigned)b1, (unsigned)(b1 >> 32));
            *(uint4*)(pT + ((size_t)(seg * 2 + 1) * NN + i) * 4) =
                make_uint4((unsigned)b2, (unsigned)(b2 >> 32), (unsigned)b3, (unsigned)(b3 >> 32));
        }
    }
}

// ---------------- K3: attn (R8 verbatim + 1-group pT prefetch) ----------------
// grid 512 = 128 itile32 x 4 heads; block 512 = 8 waves = 8 j-eighths (16 iters).
// launch_bounds(512,4): VGPR<=128, LDS 72KB => 2 blocks/CU = 16 waves/CU.
__global__ __launch_bounds__(512, 4)
void gat_attn(const uint4* __restrict__ pT4, const float* __restrict__ ipk,
              const float* __restrict__ jpkf, const unsigned char* __restrict__ VtF8,
              float* __restrict__ out) {
    const int lane = threadIdx.x & 63, js = threadIdx.x >> 6;   // j-eighth 0..7
    const int hd = blockIdx.x & 3, it32 = blockIdx.x >> 2;
    const int q = lane >> 4, r = lane & 15;
    const int i0 = it32 * 32, ia = i0 + r;
    const float cia = ipk[hd * NN + ia];
    const float cib = ipk[hd * NN + ia + 16];
    const int qs = q * 8;

    __shared__ unsigned lut[16];
    __shared__ float sacc[7][10][64][4];   // 71680 B
    if (threadIdx.x < 16) {
        unsigned m01 = (threadIdx.x * 0x204081u) & 0x01010101u;
        lut[threadIdx.x] = m01 * 0xFFu;    // byte e = 0xFF iff bit e of idx
    }
    __syncthreads();

    f32x4 acc[10] = {};
    const long ones = 0x3838383838383838L;      // fp8 e4m3 1.0 bytes

    const int it0 = js * 16;
    const float* jp = jpkf + (size_t)hd * NN * 2 + 2 * ((it0 << 5) + qs);
    const long*  vp = (const long*)(VtF8 + (size_t)(it0 * 16 + hd * 4) * 512) + lane;
    const uint4* prow = pT4 + (size_t)(js * 4) * NN + ia;

    auto iset = [&](unsigned w, float ci, f32x4* ac,
                    float4 ja, float4 jb, float4 jc, float4 jd,
                    long v0, long v1, long v2, long v3) {
        float p0 = fmaxf(ja.x, ci * ja.y);
        float p1 = fmaxf(ja.z, ci * ja.w);
        float p2 = fmaxf(jb.x, ci * jb.y);
        float p3 = fmaxf(jb.z, ci * jb.w);
        float p4 = fmaxf(jc.x, ci * jc.y);
        float p5 = fmaxf(jc.z, ci * jc.w);
        float p6 = fmaxf(jd.x, ci * jd.y);
        float p7 = fmaxf(jd.z, ci * jd.w);
        I64 af;
        af.i[0] = pkfp8x4(p0, p1, p2, p3) & (int)lut[w & 15u];
        af.i[1] = pkfp8x4(p4, p5, p6, p7) & (int)lut[(w >> 4) & 15u];
        ac[0] = __builtin_amdgcn_mfma_f32_16x16x32_fp8_fp8(af.v, v0, ac[0], 0, 0, 0);
        ac[1] = __builtin_amdgcn_mfma_f32_16x16x32_fp8_fp8(af.v, v1, ac[1], 0, 0, 0);
        ac[2] = __builtin_amdgcn_mfma_f32_16x16x32_fp8_fp8(af.v, v2, ac[2], 0, 0, 0);
        ac[3] = __builtin_amdgcn_mfma_f32_16x16x32_fp8_fp8(af.v, v3, ac[3], 0, 0, 0);
        ac[4] = __builtin_amdgcn_mfma_f32_16x16x32_fp8_fp8(af.v, ones, ac[4], 0, 0, 0);
    };

    uint4 wga = prow[0];
    uint4 wgb = prow[16];
    #pragma unroll 1
    for (int g = 0; g < 4; g++) {
        uint4 nga = wga, ngb = wgb;
        if (g < 3) {                       // prefetch next group during this one
            nga = prow[(size_t)(g + 1) * NN];
            ngb = prow[(size_t)(g + 1) * NN + 16];
        }
        #pragma unroll
        for (int u = 0; u < 4; u++) {
            unsigned wa = (u == 0 ? wga.x : u == 1 ? wga.y : u == 2 ? wga.z : wga.w) >> qs;
            unsigned wb = (u == 0 ? wgb.x : u == 1 ? wgb.y : u == 2 ? wgb.z : wgb.w) >> qs;
            const float4* jpv = (const float4*)jp;
            float4 ja = jpv[0], jb = jpv[1], jc = jpv[2], jd = jpv[3];
            long v0 = vp[0], v1 = vp[64], v2 = vp[128], v3 = vp[192];
            iset(wa, cia, acc,     ja, jb, jc, jd, v0, v1, v2, v3);
            iset(wb, cib, acc + 5, ja, jb, jc, jd, v0, v1, v2, v3);
            jp += 64; vp += 1024;
        }
        wga = nga; wgb = ngb;
    }

    // 1-sync combine: waves 1-7 dump, wave 0 accumulates.
    if (js > 0) {
        #pragma unroll
        for (int t = 0; t < 10; t++)
            *(f32x4*)&sacc[js - 1][t][lane][0] = acc[t];
    }
    __syncthreads();
    if (js == 0) {
        #pragma unroll 1
        for (int gg = 0; gg < 7; gg++)
            #pragma unroll
            for (int t = 0; t < 10; t++) {
                f32x4 o = *(const f32x4*)&sacc[gg][t][lane][0];
                acc[t][0] += o[0]; acc[t][1] += o[1];
                acc[t][2] += o[2]; acc[t][3] += o[3];
            }
        #pragma unroll
        for (int reg = 0; reg < 4; reg++) {
            float inva = 1.f / acc[4][reg];
            float invb = 1.f / acc[9][reg];
            int rowa = i0 + q * 4 + reg;
            #pragma unroll
            for (int t = 0; t < 4; t++) {
                out[(size_t)rowa * NF + hd * 64 + t * 16 + r] = acc[t][reg] * inva;
                out[(size_t)(rowa + 16) * NF + hd * 64 + t * 16 + r] = acc[t + 5][reg] * invb;
            }
        }
    }
}

extern "C" void kernel_launch(void* const* d_in, const int* in_sizes, int n_in,
                              void* d_out, int out_size, void* d_ws, size_t ws_size,
                              hipStream_t stream) {
    const float* x   = (const float*)d_in[0];
    const int*   adj = (const int*)d_in[1];
    const float* W   = (const float*)d_in[2];
    const float* a   = (const float*)d_in[3];
    float* out = (float*)d_out;

    char* ws = (char*)d_ws;
    short*         xF   = (short*)ws;                      // 4 MiB
    short*         WtF  = (short*)(ws + 4194304);          // 256 KiB
    unsigned char* VtF8 = (unsigned char*)(ws + 4456448);  // 1 MiB
    unsigned*      pT   = (unsigned*)(ws + 5505024);       // 2 MiB
    float*         ipk  = (float*)(ws + 7602176);          // 64 KiB
    float2*        jpk  = (float2*)(ws + 7667712);         // 128 KiB

    stage1  <<<1088, 256, 0, stream>>>(x, W, xF, WtF);
    stage2  <<<16640, 256, 0, stream>>>(xF, WtF, a, adj, VtF8, ipk, jpk, pT);
    gat_attn<<<512, 512, 0, stream>>>((const uint4*)pT, ipk, (const float*)jpk, VtF8, out);
}

// Round 13
// 124.604 us; speedup vs baseline: 1.2796x; 1.0286x over previous
//
#include <hip/hip_runtime.h>
#include <hip/hip_bf16.h>

// GAT forward on MI355X. N=4096, IN_F=512, OUT_F=64, HEADS=4, alpha=0.2.
//
// R12 post-mortem: pT prefetch neutral (128.2 ~= R8 127.9). attn ~22us vs
// ~6us floor, stall-dominated. R13 = R12 + two register-neutral stall cuts:
//  (1) jpk staged to LDS per block (32KB, overlaid with sacc via shared char
//      array + extra barrier) -- kills per-iter L2-latency on jp loads
//  (2) LDS LUT -> arithmetic bytemask (lut[w&15] was a per-lane gather =
//      up to 16-way bank conflict, ~130 cyc/iter/wave; R11 showed bytemask
//      only bundled with a spilling prefetch)
// K1: xpack+wpack   K2: gemmfuse+adjpack   K3: attn

#define NN 4096
#define KF 512
#define NF 256

typedef __attribute__((ext_vector_type(8))) short bf16x8;
typedef __attribute__((ext_vector_type(4))) short s16x4;
typedef __attribute__((ext_vector_type(4))) float f32x4;

union AB8 { bf16x8 v; short2 h[4]; short s[8]; int4 i4; };
union ST4 { s16x4 v; short2 h[2]; };
union I64 { long v; int i[2]; };

__device__ __forceinline__ short f2bf(float f) {
    union { float f; unsigned u; } v; v.f = f;
    unsigned r = v.u + 0x7fffu + ((v.u >> 16) & 1u);  // RNE (finite only)
    return (short)(r >> 16);
}
__device__ __forceinline__ short2 pkbf(float a, float b) {
    __hip_bfloat162 t = __float22bfloat162_rn(make_float2(a, b));
    union { __hip_bfloat162 v; short2 s; } u; u.v = t;
    return u.s;
}
__device__ __forceinline__ int pkfp8x4(float a, float b, float c, float d) {
    int p = __builtin_amdgcn_cvt_pk_fp8_f32(a, b, 0, false);
    p     = __builtin_amdgcn_cvt_pk_fp8_f32(c, d, p, true);
    return p;
}
// nibble n -> 4 bytes, byte e = 0xFF iff bit e of n (3 VALU ops, no LDS)
__device__ __forceinline__ int bytemask(unsigned n) {
    return (int)(((n * 0x204081u) & 0x01010101u) * 0xFFu);
}

// ---------------- K1: xpack (bid<1024) + wpack (bid>=1024) ----------------
__global__ __launch_bounds__(256) void stage1(const float* __restrict__ x,
                                              const float* __restrict__ W,
                                              short* __restrict__ xF,
                                              short* __restrict__ WtF) {
    if (blockIdx.x < 1024) {
        const int lane = threadIdx.x & 63, wv = threadIdx.x >> 6;
        const int i = blockIdx.x * 4 + wv;
        const float4* xp = (const float4*)(x + (size_t)i * KF + lane * 8);
        float4 xa = xp[0], xb = xp[1];
        ST4 o0, o1;
        o0.h[0] = pkbf(xa.x, xa.y); o0.h[1] = pkbf(xa.z, xa.w);
        o1.h[0] = pkbf(xb.x, xb.y); o1.h[1] = pkbf(xb.z, xb.w);
        const int kblk = lane >> 2, qk = lane & 3;
        const int jgrp = i >> 4, r = i & 15;
        short* dst = xF + ((size_t)(kblk * 256 + jgrp) * 64 + qk * 16 + r) * 8;
        *(s16x4*)dst = o0.v;
        *(s16x4*)(dst + 4) = o1.v;
    } else {
        int tid = (blockIdx.x - 1024) * 256 + threadIdx.x;   // 16384 threads
        int l = tid & 63, nt = (tid >> 6) & 3, hd = (tid >> 8) & 3, kblk = tid >> 10;
        int q = l >> 4, r = l & 15;
        int col = hd * 64 + nt * 16 + r;
        int k0 = kblk * 32 + q * 8;
        AB8 o;
        #pragma unroll
        for (int e = 0; e < 8; e++) o.s[e] = f2bf(W[(k0 + e) * NF + col]);
        *(bf16x8*)(WtF + (size_t)tid * 8) = o.v;
    }
}

// ---------------- K2: gemmfuse (bid<256) + adjpack (bid>=256) ----------------
__global__ __launch_bounds__(256) void stage2(const short* __restrict__ xF,
                                              const short* __restrict__ WtF,
                                              const float* __restrict__ a,
                                              const int* __restrict__ adj,
                                              unsigned char* __restrict__ VtF8,
                                              float* __restrict__ ipk,
                                              float2* __restrict__ jpk,
                                              unsigned* __restrict__ pT) {
    if (blockIdx.x < 256) {
        const int lane = threadIdx.x & 63, wv = threadIdx.x >> 6;
        const int q = lane >> 4, r = lane & 15;
        const int jb32 = blockIdx.x >> 1, ch = blockIdx.x & 1;
        const int rg = wv >> 1, hd = ch * 2 + (wv & 1);
        const int jgrp = jb32 * 2 + rg;

        const short* ap = xF  + ((size_t)jgrp * 64 + lane) * 8;
        const short* wp = WtF + ((size_t)(hd * 4) * 64 + lane) * 8;

        f32x4 acc[4] = {};
        #pragma unroll
        for (int kblk = 0; kblk < 16; kblk++) {
            bf16x8 av = *(const bf16x8*)(ap + (size_t)kblk * 256 * 512);
            const short* w = wp + (size_t)kblk * 16 * 512;
            #pragma unroll
            for (int nt = 0; nt < 4; nt++) {
                bf16x8 bv = *(const bf16x8*)(w + nt * 512);
                acc[nt] = __builtin_amdgcn_mfma_f32_16x16x32_bf16(av, bv, acc[nt], 0, 0, 0);
            }
        }
        const int base = rg * 16 + q * 4;
        const int qa = base >> 3, e0 = base & 7;
        #pragma unroll
        for (int nt = 0; nt < 4; nt++) {
            size_t slot = (size_t)(((jb32 * 4 + hd) * 4 + nt) * 64 + qa * 16 + r);
            *(int*)(VtF8 + slot * 8 + e0) = pkfp8x4(acc[nt][0], acc[nt][1], acc[nt][2], acc[nt][3]);
        }
        float as[4], at[4];
        #pragma unroll
        for (int nt = 0; nt < 4; nt++) { as[nt] = a[nt * 16 + r]; at[nt] = a[64 + nt * 16 + r]; }
        f32x4 sp = {}, tp = {};
        #pragma unroll
        for (int nt = 0; nt < 4; nt++)
            #pragma unroll
            for (int reg = 0; reg < 4; reg++) {
                sp[reg] += acc[nt][reg] * as[nt];
                tp[reg] += acc[nt][reg] * at[nt];
            }
        #pragma unroll
        for (int d = 1; d < 16; d <<= 1)
            #pragma unroll
            for (int reg = 0; reg < 4; reg++) {
                sp[reg] += __shfl_xor(sp[reg], d, 64);
                tp[reg] += __shfl_xor(tp[reg], d, 64);
            }
        if (r == 0) {
            #pragma unroll
            for (int reg = 0; reg < 4; reg++) {
                int j = jb32 * 32 + rg * 16 + q * 4 + reg;
                ipk[hd * NN + j] = __expf(-0.8f * sp[reg]);
                jpk[hd * NN + j] = make_float2(__expf(tp[reg]), __expf(0.2f * tp[reg]));
            }
        }
    } else {
        int gw   = ((blockIdx.x - 256) * 256 + threadIdx.x) >> 6;
        int lane = threadIdx.x & 63;
        int i = gw >> 4, seg = gw & 15;
        const int* ap = adj + (size_t)i * NN + seg * 256 + lane;
        unsigned long long b0 = __ballot(ap[0]   != 0);
        unsigned long long b1 = __ballot(ap[64]  != 0);
        unsigned long long b2 = __ballot(ap[128] != 0);
        unsigned long long b3 = __ballot(ap[192] != 0);
        if (lane == 0) {
            *(uint4*)(pT + ((size_t)(seg * 2    ) * NN + i) * 4) =
                make_uint4((unsigned)b0, (unsigned)(b0 >> 32), (unsigned)b1, (unsigned)(b1 >> 32));
            *(uint4*)(pT + ((size_t)(seg * 2 + 1) * NN + i) * 4) =
                make_uint4((unsigned)b2, (unsigned)(b2 >> 32), (unsigned)b3, (unsigned)(b3 >> 32));
        }
    }
}

// ---------------- K3: attn (R12 + jpk-in-LDS + arithmetic bytemask) ----------------
// grid 512 = 128 itile32 x 4 heads; block 512 = 8 waves = 8 j-eighths (16 iters).
// launch_bounds(512,4): VGPR<=128; LDS 70KB (sjp 32KB overlaid with sacc).
__global__ __launch_bounds__(512, 4)
void gat_attn(const uint4* __restrict__ pT4, const float* __restrict__ ipk,
              const float* __restrict__ jpkf, const unsigned char* __restrict__ VtF8,
              float* __restrict__ out) {
    const int lane = threadIdx.x & 63, js = threadIdx.x >> 6;   // j-eighth 0..7
    const int hd = blockIdx.x & 3, it32 = blockIdx.x >> 2;
    const int q = lane >> 4, r = lane & 15;
    const int i0 = it32 * 32, ia = i0 + r;
    const float cia = ipk[hd * NN + ia];
    const float cib = ipk[hd * NN + ia + 16];
    const int qs = q * 8;

    __shared__ __align__(16) char smem[71680];   // sjp (32KB) then sacc (70KB)
    float* sjp  = (float*)smem;                  // [8192] during main loop
    float* sacb = (float*)smem;                  // ((gg*10+t)*64+lane)*4 at combine

    // stage this wave's 512-j jpk slice into LDS (coalesced 16B/lane)
    {
        const float* src = jpkf + (size_t)hd * NN * 2 + js * 1024;
        float* dst = sjp + js * 1024;
        #pragma unroll
        for (int t = 0; t < 4; t++) {
            float4 v = *(const float4*)(src + (t * 64 + lane) * 4);
            *(float4*)(dst + (t * 64 + lane) * 4) = v;
        }
    }
    __syncthreads();

    f32x4 acc[10] = {};
    const long ones = 0x3838383838383838L;      // fp8 e4m3 1.0 bytes

    const int it0 = js * 16;
    const float* jp = sjp + 2 * ((it0 << 5) + qs);   // LDS reads, broadcast per q
    const long*  vp = (const long*)(VtF8 + (size_t)(it0 * 16 + hd * 4) * 512) + lane;
    const uint4* prow = pT4 + (size_t)(js * 4) * NN + ia;

    auto iset = [&](unsigned w, float ci, f32x4* ac,
                    float4 ja, float4 jb, float4 jc, float4 jd,
                    long v0, long v1, long v2, long v3) {
        float p0 = fmaxf(ja.x, ci * ja.y);
        float p1 = fmaxf(ja.z, ci * ja.w);
        float p2 = fmaxf(jb.x, ci * jb.y);
        float p3 = fmaxf(jb.z, ci * jb.w);
        float p4 = fmaxf(jc.x, ci * jc.y);
        float p5 = fmaxf(jc.z, ci * jc.w);
        float p6 = fmaxf(jd.x, ci * jd.y);
        float p7 = fmaxf(jd.z, ci * jd.w);
        I64 af;
        af.i[0] = pkfp8x4(p0, p1, p2, p3) & bytemask(w & 15u);
        af.i[1] = pkfp8x4(p4, p5, p6, p7) & bytemask((w >> 4) & 15u);
        ac[0] = __builtin_amdgcn_mfma_f32_16x16x32_fp8_fp8(af.v, v0, ac[0], 0, 0, 0);
        ac[1] = __builtin_amdgcn_mfma_f32_16x16x32_fp8_fp8(af.v, v1, ac[1], 0, 0, 0);
        ac[2] = __builtin_amdgcn_mfma_f32_16x16x32_fp8_fp8(af.v, v2, ac[2], 0, 0, 0);
        ac[3] = __builtin_amdgcn_mfma_f32_16x16x32_fp8_fp8(af.v, v3, ac[3], 0, 0, 0);
        ac[4] = __builtin_amdgcn_mfma_f32_16x16x32_fp8_fp8(af.v, ones, ac[4], 0, 0, 0);
    };

    uint4 wga = prow[0];
    uint4 wgb = prow[16];
    #pragma unroll 1
    for (int g = 0; g < 4; g++) {
        uint4 nga = wga, ngb = wgb;
        if (g < 3) {                       // prefetch next group during this one
            nga = prow[(size_t)(g + 1) * NN];
            ngb = prow[(size_t)(g + 1) * NN + 16];
        }
        #pragma unroll
        for (int u = 0; u < 4; u++) {
            unsigned wa = (u == 0 ? wga.x : u == 1 ? wga.y : u == 2 ? wga.z : wga.w) >> qs;
            unsigned wb = (u == 0 ? wgb.x : u == 1 ? wgb.y : u == 2 ? wgb.z : wgb.w) >> qs;
            const float4* jpv = (const float4*)jp;
            float4 ja = jpv[0], jb = jpv[1], jc = jpv[2], jd = jpv[3];
            long v0 = vp[0], v1 = vp[64], v2 = vp[128], v3 = vp[192];
            iset(wa, cia, acc,     ja, jb, jc, jd, v0, v1, v2, v3);
            iset(wb, cib, acc + 5, ja, jb, jc, jd, v0, v1, v2, v3);
            jp += 64; vp += 1024;
        }
        wga = nga; wgb = ngb;
    }

    // all waves done reading sjp before sacc overlays it
    __syncthreads();
    if (js > 0) {
        #pragma unroll
        for (int t = 0; t < 10; t++)
            *(f32x4*)&sacb[(((js - 1) * 10 + t) * 64 + lane) * 4] = acc[t];
    }
    __syncthreads();
    if (js == 0) {
        #pragma unroll 1
        for (int gg = 0; gg < 7; gg++)
            #pragma unroll
            for (int t = 0; t < 10; t++) {
                f32x4 o = *(const f32x4*)&sacb[((gg * 10 + t) * 64 + lane) * 4];
                acc[t][0] += o[0]; acc[t][1] += o[1];
                acc[t][2] += o[2]; acc[t][3] += o[3];
            }
        #pragma unroll
        for (int reg = 0; reg < 4; reg++) {
            float inva = 1.f / acc[4][reg];
            float invb = 1.f / acc[9][reg];
            int rowa = i0 + q * 4 + reg;
            #pragma unroll
            for (int t = 0; t < 4; t++) {
                out[(size_t)rowa * NF + hd * 64 + t * 16 + r] = acc[t][reg] * inva;
                out[(size_t)(rowa + 16) * NF + hd * 64 + t * 16 + r] = acc[t + 5][reg] * invb;
            }
        }
    }
}

extern "C" void kernel_launch(void* const* d_in, const int* in_sizes, int n_in,
                              void* d_out, int out_size, void* d_ws, size_t ws_size,
                              hipStream_t stream) {
    const float* x   = (const float*)d_in[0];
    const int*   adj = (const int*)d_in[1];
    const float* W   = (const float*)d_in[2];
    const float* a   = (const float*)d_in[3];
    float* out = (float*)d_out;

    char* ws = (char*)d_ws;
    short*         xF   = (short*)ws;                      // 4 MiB
    short*         WtF  = (short*)(ws + 4194304);          // 256 KiB
    unsigned char* VtF8 = (unsigned char*)(ws + 4456448);  // 1 MiB
    unsigned*      pT   = (unsigned*)(ws + 5505024);       // 2 MiB
    float*         ipk  = (float*)(ws + 7602176);          // 64 KiB
    float2*        jpk  = (float2*)(ws + 7667712);         // 128 KiB

    stage1  <<<1088, 256, 0, stream>>>(x, W, xF, WtF);
    stage2  <<<16640, 256, 0, stream>>>(xF, WtF, a, adj, VtF8, ipk, jpk, pT);
    gat_attn<<<512, 512, 0, stream>>>((const uint4*)pT, ipk, (const float*)jpk, VtF8, out);
}

// Round 14
// 123.682 us; speedup vs baseline: 1.2891x; 1.0075x over previous
//
#include <hip/hip_runtime.h>
#include <hip/hip_bf16.h>

// GAT forward on MI355X. N=4096, IN_F=512, OUT_F=64, HEADS=4, alpha=0.2.
//
// R13 post-mortem: jpk-LDS + bytemask -3.6us (attn ~18.5 vs ~6 floor).
// R14 = R13 + V-chain fixes: (1) nt-interleaved V layout -> 2x dwordx4
// loads/iter (was 4x dwordx2); (2) 1-iter-ahead V prefetch (8 VGPRs,
// transient) so V L2 latency hides under compute.
// K1: xpack+wpack   K2: gemmfuse+adjpack   K3: attn

#define NN 4096
#define KF 512
#define NF 256

typedef __attribute__((ext_vector_type(8))) short bf16x8;
typedef __attribute__((ext_vector_type(4))) short s16x4;
typedef __attribute__((ext_vector_type(4))) float f32x4;

union AB8 { bf16x8 v; short2 h[4]; short s[8]; int4 i4; };
union ST4 { s16x4 v; short2 h[2]; };
union I64 { long v; int i[2]; };
union V16 { int4 q; long l[2]; };

__device__ __forceinline__ short f2bf(float f) {
    union { float f; unsigned u; } v; v.f = f;
    unsigned r = v.u + 0x7fffu + ((v.u >> 16) & 1u);  // RNE (finite only)
    return (short)(r >> 16);
}
__device__ __forceinline__ short2 pkbf(float a, float b) {
    __hip_bfloat162 t = __float22bfloat162_rn(make_float2(a, b));
    union { __hip_bfloat162 v; short2 s; } u; u.v = t;
    return u.s;
}
__device__ __forceinline__ int pkfp8x4(float a, float b, float c, float d) {
    int p = __builtin_amdgcn_cvt_pk_fp8_f32(a, b, 0, false);
    p     = __builtin_amdgcn_cvt_pk_fp8_f32(c, d, p, true);
    return p;
}
// nibble n -> 4 bytes, byte e = 0xFF iff bit e of n (3 VALU ops, no LDS)
__device__ __forceinline__ int bytemask(unsigned n) {
    return (int)(((n * 0x204081u) & 0x01010101u) * 0xFFu);
}

// ---------------- K1: xpack (bid<1024) + wpack (bid>=1024) ----------------
__global__ __launch_bounds__(256) void stage1(const float* __restrict__ x,
                                              const float* __restrict__ W,
                                              short* __restrict__ xF,
                                              short* __restrict__ WtF) {
    if (blockIdx.x < 1024) {
        const int lane = threadIdx.x & 63, wv = threadIdx.x >> 6;
        const int i = blockIdx.x * 4 + wv;
        const float4* xp = (const float4*)(x + (size_t)i * KF + lane * 8);
        float4 xa = xp[0], xb = xp[1];
        ST4 o0, o1;
        o0.h[0] = pkbf(xa.x, xa.y); o0.h[1] = pkbf(xa.z, xa.w);
        o1.h[0] = pkbf(xb.x, xb.y); o1.h[1] = pkbf(xb.z, xb.w);
        const int kblk = lane >> 2, qk = lane & 3;
        const int jgrp = i >> 4, r = i & 15;
        short* dst = xF + ((size_t)(kblk * 256 + jgrp) * 64 + qk * 16 + r) * 8;
        *(s16x4*)dst = o0.v;
        *(s16x4*)(dst + 4) = o1.v;
    } else {
        int tid = (blockIdx.x - 1024) * 256 + threadIdx.x;   // 16384 threads
        int l = tid & 63, nt = (tid >> 6) & 3, hd = (tid >> 8) & 3, kblk = tid >> 10;
        int q = l >> 4, r = l & 15;
        int col = hd * 64 + nt * 16 + r;
        int k0 = kblk * 32 + q * 8;
        AB8 o;
        #pragma unroll
        for (int e = 0; e < 8; e++) o.s[e] = f2bf(W[(k0 + e) * NF + col]);
        *(bf16x8*)(WtF + (size_t)tid * 8) = o.v;
    }
}

// ---------------- K2: gemmfuse (bid<256) + adjpack (bid>=256) ----------------
__global__ __launch_bounds__(256) void stage2(const short* __restrict__ xF,
                                              const short* __restrict__ WtF,
                                              const float* __restrict__ a,
                                              const int* __restrict__ adj,
                                              unsigned char* __restrict__ VtF8,
                                              float* __restrict__ ipk,
                                              float2* __restrict__ jpk,
                                              unsigned* __restrict__ pT) {
    if (blockIdx.x < 256) {
        const int lane = threadIdx.x & 63, wv = threadIdx.x >> 6;
        const int q = lane >> 4, r = lane & 15;
        const int jb32 = blockIdx.x >> 1, ch = blockIdx.x & 1;
        const int rg = wv >> 1, hd = ch * 2 + (wv & 1);
        const int jgrp = jb32 * 2 + rg;

        const short* ap = xF  + ((size_t)jgrp * 64 + lane) * 8;
        const short* wp = WtF + ((size_t)(hd * 4) * 64 + lane) * 8;

        f32x4 acc[4] = {};
        #pragma unroll
        for (int kblk = 0; kblk < 16; kblk++) {
            bf16x8 av = *(const bf16x8*)(ap + (size_t)kblk * 256 * 512);
            const short* w = wp + (size_t)kblk * 16 * 512;
            #pragma unroll
            for (int nt = 0; nt < 4; nt++) {
                bf16x8 bv = *(const bf16x8*)(w + nt * 512);
                acc[nt] = __builtin_amdgcn_mfma_f32_16x16x32_bf16(av, bv, acc[nt], 0, 0, 0);
            }
        }
        // V store, nt-interleaved: addr = ((jb32*4+hd)*64 + qa*16+r)*32 + nt*8 + e0
        const int base = rg * 16 + q * 4;
        const int qa = base >> 3, e0 = base & 7;
        #pragma unroll
        for (int nt = 0; nt < 4; nt++) {
            size_t addr = (((size_t)((jb32 * 4 + hd) * 64 + qa * 16 + r)) * 4 + nt) * 8 + e0;
            *(int*)(VtF8 + addr) = pkfp8x4(acc[nt][0], acc[nt][1], acc[nt][2], acc[nt][3]);
        }
        float as[4], at[4];
        #pragma unroll
        for (int nt = 0; nt < 4; nt++) { as[nt] = a[nt * 16 + r]; at[nt] = a[64 + nt * 16 + r]; }
        f32x4 sp = {}, tp = {};
        #pragma unroll
        for (int nt = 0; nt < 4; nt++)
            #pragma unroll
            for (int reg = 0; reg < 4; reg++) {
                sp[reg] += acc[nt][reg] * as[nt];
                tp[reg] += acc[nt][reg] * at[nt];
            }
        #pragma unroll
        for (int d = 1; d < 16; d <<= 1)
            #pragma unroll
            for (int reg = 0; reg < 4; reg++) {
                sp[reg] += __shfl_xor(sp[reg], d, 64);
                tp[reg] += __shfl_xor(tp[reg], d, 64);
            }
        if (r == 0) {
            #pragma unroll
            for (int reg = 0; reg < 4; reg++) {
                int j = jb32 * 32 + rg * 16 + q * 4 + reg;
                ipk[hd * NN + j] = __expf(-0.8f * sp[reg]);
                jpk[hd * NN + j] = make_float2(__expf(tp[reg]), __expf(0.2f * tp[reg]));
            }
        }
    } else {
        int gw   = ((blockIdx.x - 256) * 256 + threadIdx.x) >> 6;
        int lane = threadIdx.x & 63;
        int i = gw >> 4, seg = gw & 15;
        const int* ap = adj + (size_t)i * NN + seg * 256 + lane;
        unsigned long long b0 = __ballot(ap[0]   != 0);
        unsigned long long b1 = __ballot(ap[64]  != 0);
        unsigned long long b2 = __ballot(ap[128] != 0);
        unsigned long long b3 = __ballot(ap[192] != 0);
        if (lane == 0) {
            *(uint4*)(pT + ((size_t)(seg * 2    ) * NN + i) * 4) =
                make_uint4((unsigned)b0, (unsigned)(b0 >> 32), (unsigned)b1, (unsigned)(b1 >> 32));
            *(uint4*)(pT + ((size_t)(seg * 2 + 1) * NN + i) * 4) =
                make_uint4((unsigned)b2, (unsigned)(b2 >> 32), (unsigned)b3, (unsigned)(b3 >> 32));
        }
    }
}

// ---------------- K3: attn (R13 + interleaved V dwordx4 + 1-iter V prefetch) ----------------
// grid 512 = 128 itile32 x 4 heads; block 512 = 8 waves = 8 j-eighths (16 iters).
// launch_bounds(512,4): VGPR<=128; LDS 70KB (sjp 32KB overlaid with sacc).
__global__ __launch_bounds__(512, 4)
void gat_attn(const uint4* __restrict__ pT4, const float* __restrict__ ipk,
              const float* __restrict__ jpkf, const unsigned char* __restrict__ VtF8,
              float* __restrict__ out) {
    const int lane = threadIdx.x & 63, js = threadIdx.x >> 6;   // j-eighth 0..7
    const int hd = blockIdx.x & 3, it32 = blockIdx.x >> 2;
    const int q = lane >> 4, r = lane & 15;
    const int i0 = it32 * 32, ia = i0 + r;
    const float cia = ipk[hd * NN + ia];
    const float cib = ipk[hd * NN + ia + 16];
    const int qs = q * 8;

    __shared__ __align__(16) char smem[71680];   // sjp (32KB) then sacc (70KB)
    float* sjp  = (float*)smem;                  // [8192] during main loop
    float* sacb = (float*)smem;                  // combine buffer afterwards

    // stage this wave's 512-j jpk slice into LDS (coalesced 16B/lane)
    {
        const float* src = jpkf + (size_t)hd * NN * 2 + js * 1024;
        float* dst = sjp + js * 1024;
        #pragma unroll
        for (int t = 0; t < 4; t++) {
            float4 v = *(const float4*)(src + (t * 64 + lane) * 4);
            *(float4*)(dst + (t * 64 + lane) * 4) = v;
        }
    }
    __syncthreads();

    f32x4 acc[10] = {};
    const long ones = 0x3838383838383838L;      // fp8 e4m3 1.0 bytes

    const int it0 = js * 16;
    const float* jp = sjp + 2 * ((it0 << 5) + qs);   // LDS reads
    const int4*  vq = (const int4*)(VtF8 + ((size_t)(it0 * 4 + hd) * 64 + lane) * 32);
    const uint4* prow = pT4 + (size_t)(js * 4) * NN + ia;

    auto iset = [&](unsigned w, float ci, f32x4* ac,
                    float4 ja, float4 jb, float4 jc, float4 jd,
                    long v0, long v1, long v2, long v3) {
        float p0 = fmaxf(ja.x, ci * ja.y);
        float p1 = fmaxf(ja.z, ci * ja.w);
        float p2 = fmaxf(jb.x, ci * jb.y);
        float p3 = fmaxf(jb.z, ci * jb.w);
        float p4 = fmaxf(jc.x, ci * jc.y);
        float p5 = fmaxf(jc.z, ci * jc.w);
        float p6 = fmaxf(jd.x, ci * jd.y);
        float p7 = fmaxf(jd.z, ci * jd.w);
        I64 af;
        af.i[0] = pkfp8x4(p0, p1, p2, p3) & bytemask(w & 15u);
        af.i[1] = pkfp8x4(p4, p5, p6, p7) & bytemask((w >> 4) & 15u);
        ac[0] = __builtin_amdgcn_mfma_f32_16x16x32_fp8_fp8(af.v, v0, ac[0], 0, 0, 0);
        ac[1] = __builtin_amdgcn_mfma_f32_16x16x32_fp8_fp8(af.v, v1, ac[1], 0, 0, 0);
        ac[2] = __builtin_amdgcn_mfma_f32_16x16x32_fp8_fp8(af.v, v2, ac[2], 0, 0, 0);
        ac[3] = __builtin_amdgcn_mfma_f32_16x16x32_fp8_fp8(af.v, v3, ac[3], 0, 0, 0);
        ac[4] = __builtin_amdgcn_mfma_f32_16x16x32_fp8_fp8(af.v, ones, ac[4], 0, 0, 0);
    };

    uint4 wga = prow[0];
    uint4 wgb = prow[16];
    V16 va, vb;
    va.q = vq[0]; vb.q = vq[1];
    #pragma unroll 1
    for (int g = 0; g < 4; g++) {
        uint4 nga = wga, ngb = wgb;
        if (g < 3) {                       // prefetch next pT group
            nga = prow[(size_t)(g + 1) * NN];
            ngb = prow[(size_t)(g + 1) * NN + 16];
        }
        #pragma unroll
        for (int u = 0; u < 4; u++) {
            V16 na, nb;                    // next-iter V prefetch (tail read harmless)
            na.q = vq[512]; nb.q = vq[513];
            unsigned wa = (u == 0 ? wga.x : u == 1 ? wga.y : u == 2 ? wga.z : wga.w) >> qs;
            unsigned wb = (u == 0 ? wgb.x : u == 1 ? wgb.y : u == 2 ? wgb.z : wgb.w) >> qs;
            const float4* jpv = (const float4*)jp;
            float4 ja = jpv[0], jb = jpv[1], jc = jpv[2], jd = jpv[3];
            iset(wa, cia, acc,     ja, jb, jc, jd, va.l[0], va.l[1], vb.l[0], vb.l[1]);
            iset(wb, cib, acc + 5, ja, jb, jc, jd, va.l[0], va.l[1], vb.l[0], vb.l[1]);
            jp += 64; vq += 512;
            va = na; vb = nb;
        }
        wga = nga; wgb = ngb;
    }

    // all waves done reading sjp before sacc overlays it
    __syncthreads();
    if (js > 0) {
        #pragma unroll
        for (int t = 0; t < 10; t++)
            *(f32x4*)&sacb[(((js - 1) * 10 + t) * 64 + lane) * 4] = acc[t];
    }
    __syncthreads();
    if (js == 0) {
        #pragma unroll 1
        for (int gg = 0; gg < 7; gg++)
            #pragma unroll
            for (int t = 0; t < 10; t++) {
                f32x4 o = *(const f32x4*)&sacb[((gg * 10 + t) * 64 + lane) * 4];
                acc[t][0] += o[0]; acc[t][1] += o[1];
                acc[t][2] += o[2]; acc[t][3] += o[3];
            }
        #pragma unroll
        for (int reg = 0; reg < 4; reg++) {
            float inva = 1.f / acc[4][reg];
            float invb = 1.f / acc[9][reg];
            int rowa = i0 + q * 4 + reg;
            #pragma unroll
            for (int t = 0; t < 4; t++) {
                out[(size_t)rowa * NF + hd * 64 + t * 16 + r] = acc[t][reg] * inva;
                out[(size_t)(rowa + 16) * NF + hd * 64 + t * 16 + r] = acc[t + 5][reg] * invb;
            }
        }
    }
}

extern "C" void kernel_launch(void* const* d_in, const int* in_sizes, int n_in,
                              void* d_out, int out_size, void* d_ws, size_t ws_size,
                              hipStream_t stream) {
    const float* x   = (const float*)d_in[0];
    const int*   adj = (const int*)d_in[1];
    const float* W   = (const float*)d_in[2];
    const float* a   = (const float*)d_in[3];
    float* out = (float*)d_out;

    char* ws = (char*)d_ws;
    short*         xF   = (short*)ws;                      // 4 MiB
    short*         WtF  = (short*)(ws + 4194304);          // 256 KiB
    unsigned char* VtF8 = (unsigned char*)(ws + 4456448);  // 1 MiB
    unsigned*      pT   = (unsigned*)(ws + 5505024);       // 2 MiB
    float*         ipk  = (float*)(ws + 7602176);          // 64 KiB
    float2*        jpk  = (float2*)(ws + 7667712);         // 128 KiB

    stage1  <<<1088, 256, 0, stream>>>(x, W, xF, WtF);
    stage2  <<<16640, 256, 0, stream>>>(xF, WtF, a, adj, VtF8, ipk, jpk, pT);
    gat_attn<<<512, 512, 0, stream>>>((const uint4*)pT, ipk, (const float*)jpk, VtF8, out);
}